// Round 10
// baseline (1284.583 us; speedup 1.0000x reference)
//
#include <hip/hip_runtime.h>

#define NSTEP 10

typedef __attribute__((ext_vector_type(8))) short bf16x8;   // 8 bf16 = 4 VGPRs
typedef __attribute__((ext_vector_type(4))) float f32x4;    // MFMA C/D

// ---------------------------------------------------------------------------
// Prep 1: transpose W1 [256][250] -> W1T [250][256]
// ---------------------------------------------------------------------------
extern "C" __global__ void __launch_bounds__(256) snn_prep(
    const float* __restrict__ W1, float* __restrict__ W1T)
{
    int i0 = blockIdx.x * 256 + threadIdx.x;
    int stride = gridDim.x * 256;
    for (int idx = i0; idx < 250 * 256; idx += stride) {
        int k = idx >> 8;
        int n = idx & 255;
        W1T[idx] = W1[n * 250 + k];
    }
}

// ---------------------------------------------------------------------------
// Prep 2: exact 3-way bf16 split of W2 into MFMA B-fragment layout
// (identical to R5/R7). [j-strip 0..7][split 0..2][slab 0..7][lane][8] (192KB)
// ---------------------------------------------------------------------------
__device__ __forceinline__ unsigned int bf16_rne_hi(float f) {
    unsigned int u = __float_as_uint(f);
    return (u + 0x7FFFu + ((u >> 16) & 1u)) & 0xFFFF0000u;
}

extern "C" __global__ void __launch_bounds__(256) snn_prep2(
    const float* __restrict__ W2, unsigned short* __restrict__ W2F)
{
    int idx = blockIdx.x * 256 + threadIdx.x;   // 8*3*8*64 = 12288 items
    if (idx >= 8 * 3 * 8 * 64) return;
    int lane  = idx & 63;
    int slab  = (idx >> 6) & 7;
    int split = (idx >> 9) % 3;
    int w     = idx / (3 * 8 * 64);
    int j  = w * 16 + (lane & 15);
    int k0 = slab * 32 + (lane >> 4) * 8;
    unsigned short res[8];
    #pragma unroll
    for (int e = 0; e < 8; ++e) {
        float wval = W2[j * 256 + k0 + e];
        unsigned int u1 = bf16_rne_hi(wval);
        float r1 = __fsub_rn(wval, __uint_as_float(u1));
        unsigned int u2 = bf16_rne_hi(r1);
        float r2 = __fsub_rn(r1, __uint_as_float(u2));
        unsigned int u3 = bf16_rne_hi(r2);
        unsigned int sel = (split == 0) ? u1 : (split == 1) ? u2 : u3;
        res[e] = (unsigned short)(sel >> 16);
    }
    *(uint4*)&W2F[(((w * 3 + split) * 8 + slab) << 9) + lane * 8] =
        *(uint4*)res;
}

// ---------------------------------------------------------------------------
// Main fused SNN kernel. 64 samples/block, 512 threads, 10 steps fused.
//
// R10 = R7 (passed, absmax 0.0, 1385 us) + two scheduling-only changes:
//   1. prologue k-loop unroll 2 -> 5 (more loads in flight; chain order
//      per accumulator unchanged - strictly k-ascending)
//   2. phase B: explicit 1-slab-ahead prefetch of B-frags (L2) and A-frags
//      (LDS) into named registers; MFMA order byte-identical to R7.
// __launch_bounds__ stays (512,2): R8/R9 proved a 128-reg cap on this
// working set mis-executes (absmax 2.0 both times) - never cap below
// natural allocation.
//
// LDS (bytes): s1bf [0,32768) | s2Lb [32768,41984) | W3L [41984,46080)
//              pL [46080,51200) | bL [51200,51736)
// Prologue alias: xT f32[250][68] @0 (68000 B), consumed before W3L staged.
// ---------------------------------------------------------------------------
extern "C" __global__ void __launch_bounds__(512, 2) snn_main(
    const float* __restrict__ x,
    const float* __restrict__ b1,
    const float* __restrict__ b2g,
    const float* __restrict__ W3,
    const float* __restrict__ b3,
    const float* __restrict__ W1T,
    const unsigned short* __restrict__ W2F,
    float* __restrict__ out)
{
    __shared__ __align__(16) char ldsraw[68000];
    char* s1bf = ldsraw;                                     // [64][512B] bf16
    unsigned char* s2Lb = (unsigned char*)(ldsraw + 32768);  // [128][72] u8
    float* W3L = (float*)(ldsraw + 41984);                   // [128][8]
    float* pL  = (float*)(ldsraw + 46080);                   // [20][64]
    float* bL  = (float*)(ldsraw + 51200);                   // [133]
    float* xT  = (float*)(ldsraw);                           // prologue alias

    const int t    = threadIdx.x;
    const int nt   = t & 15;
    const int st   = t >> 4;          // 0..31
    const int s0a  = st * 2;
    const int n0   = nt * 16;
    const int lane = t & 63;
    const int wv   = t >> 6;          // 0..7 (j-strip)
    const int l15  = lane & 15;
    const int lq   = lane >> 4;       // 0..3
    const int sBase = blockIdx.x * 64;

    // ---- prologue step 1: stage x tile transposed into LDS (coalesced) ----
    for (int i = t; i < 64 * 250; i += 512) {
        int sl = i / 250;
        int kl = i - sl * 250;
        xT[kl * 68 + sl] = x[(sBase + sl) * 250 + kl];
    }
    __syncthreads();

    // ---- prologue step 2: cur1 = x @ W1.T (chain bit-identical to R7;
    //      unroll 5 only raises load-level parallelism) ----
    float cur1[16][2];
    #pragma unroll
    for (int i = 0; i < 16; ++i) { cur1[i][0] = 0.0f; cur1[i][1] = 0.0f; }

    #pragma unroll 5
    for (int k = 0; k < 250; ++k) {
        const float2 xp = *(const float2*)&xT[k * 68 + s0a];
        const float x0 = xp.x;
        const float x1 = xp.y;
        float w[16];
        *(float4*)&w[0]  = *(const float4*)&W1T[k * 256 + n0];
        *(float4*)&w[4]  = *(const float4*)&W1T[k * 256 + n0 + 4];
        *(float4*)&w[8]  = *(const float4*)&W1T[k * 256 + n0 + 8];
        *(float4*)&w[12] = *(const float4*)&W1T[k * 256 + n0 + 12];
        #pragma unroll
        for (int i = 0; i < 16; ++i) {
            cur1[i][0] = fmaf(w[i], x0, cur1[i][0]);
            cur1[i][1] = fmaf(w[i], x1, cur1[i][1]);
        }
    }
    {
        float bb[16];
        *(float4*)&bb[0]  = *(const float4*)&b1[n0];
        *(float4*)&bb[4]  = *(const float4*)&b1[n0 + 4];
        *(float4*)&bb[8]  = *(const float4*)&b1[n0 + 8];
        *(float4*)&bb[12] = *(const float4*)&b1[n0 + 12];
        #pragma unroll
        for (int i = 0; i < 16; ++i) {
            cur1[i][0] = __fadd_rn(cur1[i][0], bb[i]);
            cur1[i][1] = __fadd_rn(cur1[i][1], bb[i]);
        }
    }
    __syncthreads();   // xT fully consumed; its region may be reused

    // ---- prologue step 3: stage W3 (transposed, padded to 8) + biases ----
    for (int idx = t; idx < 640; idx += 512) {
        int o = idx >> 7;             // W3 is [5][128]
        int j = idx & 127;
        W3L[j * 8 + o] = W3[idx];
    }
    if (t < 128) bL[t] = b2g[t];
    if (t < 5)   bL[128 + t] = b3[t];
    __syncthreads();   // W3L/bL staged

    // ---- persistent state (identical to R7) ----
    float m1[16][2];
    #pragma unroll
    for (int i = 0; i < 16; ++i) { m1[i][0] = 0.0f; m1[i][1] = 0.0f; }
    float m2[4][4];                   // [m-tile][reg]
    #pragma unroll
    for (int mt = 0; mt < 4; ++mt)
        #pragma unroll
        for (int rg = 0; rg < 4; ++rg) m2[mt][rg] = 0.0f;
    float m3 = 0.0f, acc3 = 0.0f;

    const unsigned short* fb = W2F + (wv * 24) * 512 + lane * 8;
    const int keyB   = (lane & 7) << 4;   // s1 fragment-read swizzle key
    const int chunkq = lq << 4;
    const int jC     = wv * 16 + l15;     // this lane's layer-2 neuron
    const int keyC2  = ((jC >> 2) & 7) << 3;

    #pragma unroll 1
    for (int stp = 0; stp < NSTEP; ++stp) {
        // ========== A: layer-1 LIF + bf16 spikes -> LDS (identical to R7) ===
        {
            unsigned int dwa[2][8];
            #pragma unroll
            for (int i = 0; i < 16; ++i) {
                #pragma unroll
                for (int s = 0; s < 2; ++s) {
                    float m = m1[i][s];
                    float r = (m > 1.0f) ? 1.0f : 0.0f;
                    m = __fsub_rn(__fadd_rn(__fmul_rn(0.9f, m), cur1[i][s]), r);
                    m1[i][s] = m;
                    unsigned int bits = (m > 1.0f) ? 0x3F80u : 0u;  // bf16 1.0
                    if (i & 1) dwa[s][i >> 1] |= bits << 16;
                    else       dwa[s][i >> 1]  = bits;
                }
            }
            #pragma unroll
            for (int s = 0; s < 2; ++s) {
                const int row = s0a + s;
                const int key = row & 7;
                char* rp = s1bf + row * 512;
                uint4 lo = make_uint4(dwa[s][0], dwa[s][1], dwa[s][2], dwa[s][3]);
                uint4 hi = make_uint4(dwa[s][4], dwa[s][5], dwa[s][6], dwa[s][7]);
                *(uint4*)(rp + (((2 * nt + 0) ^ key) << 4)) = lo;
                *(uint4*)(rp + (((2 * nt + 1) ^ key) << 4)) = hi;
            }
        }
        __syncthreads();   // bar1: s1 ready

        // ========== B: cur2 = s1 @ W2.T via MFMA ============================
        // MFMA order byte-identical to R5/R7; only the loads are software-
        // pipelined one slab ahead (prefetch into named regs, full unroll).
        f32x4 acc[4];
        {
            const f32x4 z = {0.0f, 0.0f, 0.0f, 0.0f};
            acc[0] = z; acc[1] = z; acc[2] = z; acc[3] = z;
        }
        bf16x8 B2c, B1c, B0c, A0c, A1c, A2c, A3c;
        {
            const int coff = (0 * 64 + chunkq) ^ keyB;
            B2c = *(const bf16x8*)(fb + (16 + 0) * 512);
            B1c = *(const bf16x8*)(fb + (8  + 0) * 512);
            B0c = *(const bf16x8*)(fb + (0  + 0) * 512);
            A0c = *(const bf16x8*)(s1bf + (l15     ) * 512 + coff);
            A1c = *(const bf16x8*)(s1bf + (l15 + 16) * 512 + coff);
            A2c = *(const bf16x8*)(s1bf + (l15 + 32) * 512 + coff);
            A3c = *(const bf16x8*)(s1bf + (l15 + 48) * 512 + coff);
        }
        #pragma unroll
        for (int slab = 0; slab < 8; ++slab) {
            bf16x8 B2n, B1n, B0n, A0n, A1n, A2n, A3n;
            if (slab < 7) {
                const int coffn = ((slab + 1) * 64 + chunkq) ^ keyB;
                B2n = *(const bf16x8*)(fb + (16 + slab + 1) * 512);
                B1n = *(const bf16x8*)(fb + (8  + slab + 1) * 512);
                B0n = *(const bf16x8*)(fb + (0  + slab + 1) * 512);
                A0n = *(const bf16x8*)(s1bf + (l15     ) * 512 + coffn);
                A1n = *(const bf16x8*)(s1bf + (l15 + 16) * 512 + coffn);
                A2n = *(const bf16x8*)(s1bf + (l15 + 32) * 512 + coffn);
                A3n = *(const bf16x8*)(s1bf + (l15 + 48) * 512 + coffn);
            }
            acc[0] = __builtin_amdgcn_mfma_f32_16x16x32_bf16(A0c, B2c, acc[0], 0, 0, 0);
            acc[1] = __builtin_amdgcn_mfma_f32_16x16x32_bf16(A1c, B2c, acc[1], 0, 0, 0);
            acc[2] = __builtin_amdgcn_mfma_f32_16x16x32_bf16(A2c, B2c, acc[2], 0, 0, 0);
            acc[3] = __builtin_amdgcn_mfma_f32_16x16x32_bf16(A3c, B2c, acc[3], 0, 0, 0);
            acc[0] = __builtin_amdgcn_mfma_f32_16x16x32_bf16(A0c, B1c, acc[0], 0, 0, 0);
            acc[1] = __builtin_amdgcn_mfma_f32_16x16x32_bf16(A1c, B1c, acc[1], 0, 0, 0);
            acc[2] = __builtin_amdgcn_mfma_f32_16x16x32_bf16(A2c, B1c, acc[2], 0, 0, 0);
            acc[3] = __builtin_amdgcn_mfma_f32_16x16x32_bf16(A3c, B1c, acc[3], 0, 0, 0);
            acc[0] = __builtin_amdgcn_mfma_f32_16x16x32_bf16(A0c, B0c, acc[0], 0, 0, 0);
            acc[1] = __builtin_amdgcn_mfma_f32_16x16x32_bf16(A1c, B0c, acc[1], 0, 0, 0);
            acc[2] = __builtin_amdgcn_mfma_f32_16x16x32_bf16(A2c, B0c, acc[2], 0, 0, 0);
            acc[3] = __builtin_amdgcn_mfma_f32_16x16x32_bf16(A3c, B0c, acc[3], 0, 0, 0);
            if (slab < 7) {
                B2c = B2n; B1c = B1n; B0c = B0n;
                A0c = A0n; A1c = A1n; A2c = A2n; A3c = A3n;
            }
        }

        // ========== C: layer-2 LIF + u8 spikes -> LDS (identical to R7) =====
        {
            const float bj = bL[jC];
            #pragma unroll
            for (int mt = 0; mt < 4; ++mt) {
                unsigned int pk = 0;
                #pragma unroll
                for (int rg = 0; rg < 4; ++rg) {
                    float c2 = __fadd_rn(acc[mt][rg], bj);
                    float m = m2[mt][rg];
                    float r = (m > 1.0f) ? 1.0f : 0.0f;
                    m = __fsub_rn(__fadd_rn(__fmul_rn(0.9f, m), c2), r);
                    m2[mt][rg] = m;
                    if (m > 1.0f) pk |= 1u << (8 * rg);
                }
                const int smp0 = mt * 16 + lq * 4;
                *(unsigned int*)&s2Lb[jC * 72 + (smp0 ^ keyC2)] = pk;
            }
        }
        __syncthreads();   // bar2: s2 ready

        // ========== D: layer-3 partial dots (identical to R7) ==========
        if (t < 256) {
            const int sl = t & 63;
            const int jr = t >> 6;
            float part[5] = {0.0f, 0.0f, 0.0f, 0.0f, 0.0f};
            #pragma unroll 8
            for (int jj = 0; jj < 32; ++jj) {
                const int j = jr * 32 + jj;
                const float s2v =
                    (float)s2Lb[j * 72 + (sl ^ (((j >> 2) & 7) << 3))];
                const float4 w3a = *(const float4*)&W3L[j * 8];
                const float  w3e = W3L[j * 8 + 4];
                part[0] = fmaf(w3a.x, s2v, part[0]);
                part[1] = fmaf(w3a.y, s2v, part[1]);
                part[2] = fmaf(w3a.z, s2v, part[2]);
                part[3] = fmaf(w3a.w, s2v, part[3]);
                part[4] = fmaf(w3e,   s2v, part[4]);
            }
            #pragma unroll
            for (int o = 0; o < 5; ++o)
                pL[(o * 4 + jr) * 64 + sl] = part[o];
        }
        __syncthreads();   // bar3: partials ready

        // ========== E: layer-3 LIF + spike count (identical to R7) ==========
        if (t < 320) {
            const int o  = t >> 6;
            const int sl = t & 63;
            float c3 = pL[(o * 4 + 0) * 64 + sl];
            c3 += pL[(o * 4 + 1) * 64 + sl];
            c3 += pL[(o * 4 + 2) * 64 + sl];
            c3 += pL[(o * 4 + 3) * 64 + sl];
            c3 = __fadd_rn(c3, bL[128 + o]);
            float m = m3;
            float r = (m > 1.0f) ? 1.0f : 0.0f;
            m = __fsub_rn(__fadd_rn(__fmul_rn(0.9f, m), c3), r);
            m3 = m;
            if (m > 1.0f) acc3 += 1.0f;
        }
    }

    // ---- epilogue ----
    if (t < 320) {
        out[(sBase + (t & 63)) * 5 + (t >> 6)] = acc3;
    }
}

extern "C" void kernel_launch(void* const* d_in, const int* in_sizes, int n_in,
                              void* d_out, int out_size, void* d_ws, size_t ws_size,
                              hipStream_t stream) {
    const float* x  = (const float*)d_in[0];
    const float* W1 = (const float*)d_in[1];
    const float* b1 = (const float*)d_in[2];
    const float* W2 = (const float*)d_in[3];
    const float* b2 = (const float*)d_in[4];
    const float* W3 = (const float*)d_in[5];
    const float* b3 = (const float*)d_in[6];
    float* out = (float*)d_out;

    float* W1T = (float*)d_ws;                                     // 256 KB
    unsigned short* W2F = (unsigned short*)((char*)d_ws + 262144); // 192 KB

    const int B = in_sizes[0] / 250;      // 131072
    const int nwg = B / 64;               // 2048

    snn_prep <<<64, 256, 0, stream>>>(W1, W1T);
    snn_prep2<<<48, 256, 0, stream>>>(W2, W2F);
    snn_main <<<nwg, 512, 0, stream>>>(x, b1, b2, W3, b3, W1T, W2F, out);
}